// Round 11
// baseline (390.270 us; speedup 1.0000x reference)
//
#include <hip/hip_runtime.h>

typedef __bf16 bf16;
typedef float  f32x4  __attribute__((ext_vector_type(4)));
typedef float  f32x2  __attribute__((ext_vector_type(2)));
typedef float  f32x16 __attribute__((ext_vector_type(16)));
typedef __bf16 bf16x8 __attribute__((ext_vector_type(8)));
typedef __bf16 bf16x4 __attribute__((ext_vector_type(4)));
typedef unsigned short ushort4_ __attribute__((ext_vector_type(4)));
typedef unsigned int   uint2_   __attribute__((ext_vector_type(2)));

typedef unsigned int __attribute__((address_space(1))) uint_g;
typedef unsigned int __attribute__((address_space(3))) uint_l;

#define DEV __device__ __forceinline__

DEV void gload16(const void* g, void* l) {
  // async global->LDS, 16B per lane; LDS dst is wave-uniform base + lane*16
  __builtin_amdgcn_global_load_lds((uint_g*)g, (uint_l*)l, 16, 0, 0);
}

#define PHASE_SYNC do { \
  asm volatile("s_barrier" ::: "memory"); \
  asm volatile("s_waitcnt lgkmcnt(0)" ::: "memory"); \
  __builtin_amdgcn_sched_barrier(0); } while (0)

// ---------------- fp32 -> bf16 convert (vectorized) ----------------
__global__ void k_cvt(const float* __restrict__ in, bf16* __restrict__ out) {
  int i = blockIdx.x * 256 + threadIdx.x;          // one float4 per thread
  f32x4 v = *((const f32x4*)in + i);
  bf16x4 o;
  o[0] = (bf16)v[0]; o[1] = (bf16)v[1]; o[2] = (bf16)v[2]; o[3] = (bf16)v[3];
  *((bf16x4*)out + i) = o;
}

// ---------------- [K][N] fp32 -> [N][K] bf16 transpose ----------------
__global__ void k_transpose_cvt(const float* __restrict__ in, bf16* __restrict__ out,
                                int K, int N) {
  __shared__ bf16 tile[64][65];
  int n0 = blockIdx.x * 64, k0 = blockIdx.y * 64;
  int tx = threadIdx.x & 63, ty = threadIdx.x >> 6;
#pragma unroll
  for (int r = 0; r < 64; r += 4)
    tile[r + ty][tx] = (bf16)in[(size_t)(k0 + r + ty) * N + n0 + tx];
  __syncthreads();
#pragma unroll
  for (int r = 0; r < 64; r += 4)
    out[(size_t)(n0 + r + ty) * K + k0 + tx] = tile[tx][r + ty];
}

// ---------------- RoPE cos/sin table: [T][64] of (cos,sin) ----------------
__global__ void k_rope_tab(f32x2* __restrict__ tab) {
  int idx = blockIdx.x * 256 + threadIdx.x;   // T*64
  int t = idx >> 6, i = idx & 63;
  float inv = powf(10000.f, -(float)i * (1.f / 64.f));
  float ang = (float)t * inv;
  f32x2 cs; cs[0] = cosf(ang); cs[1] = sinf(ang);
  tab[idx] = cs;
}

// ---------------- 256x256 deep-pipelined GEMM: C = A @ Bt^T ----------------
// R8 schedule (best measured): 4 phases, stages issued P0-P2, b0 held in regs,
// single vmcnt(0) drain after the last MFMA cluster.
// MODE 0: C fp32 [M][2048].  MODE 1: QKV split (Q bf16 / K bf16 / V-transposed bf16).
template <int MODE>
__global__ __launch_bounds__(512, 2) void k_gemm256(const bf16* __restrict__ A,
                                                    const bf16* __restrict__ Bt,
                                                    void* __restrict__ Cq,
                                                    bf16* __restrict__ Ck,
                                                    bf16* __restrict__ Cv,
                                                    int K) {
  __shared__ bf16 Asm[2][256 * 64];
  __shared__ bf16 Bsm[2][256 * 64];
  const int tid = threadIdx.x;
  const int w = tid >> 6, l = tid & 63, lr = l & 15, lg = l >> 4;
  const int wr = w >> 2, wc = w & 3;
  const int bn = blockIdx.x, bm = blockIdx.y;

  const int srow = tid >> 3;                                    // 0..63
  const int scb = ((tid & 7) << 4) ^ ((srow & 7) << 4);         // pre-swizzled col byte
  const bf16* Ag = A  + ((size_t)(bm * 256) + srow) * K;
  const bf16* Bg = Bt + ((size_t)(bn * 256) + srow) * K;
  const int ldsbase = w << 10;                                  // per-wave 1KB slice

  auto stA = [&](int buf, int s, int k0) {
    gload16((const char*)Ag + ((size_t)(s * 64) * K + k0) * 2 + scb,
            (char*)&Asm[buf][0] + s * 8192 + ldsbase);
  };
  auto stB = [&](int buf, int s, int k0) {
    gload16((const char*)Bg + ((size_t)(s * 64) * K + k0) * 2 + scb,
            (char*)&Bsm[buf][0] + s * 8192 + ldsbase);
  };
  auto ldA = [&](int buf, int mf, int kk) -> bf16x8 {
    int row = wr * 128 + mf * 16 + lr;
    return *(const bf16x8*)((const char*)&Asm[buf][0] + row * 128 +
                            ((kk * 64 + lg * 16) ^ ((lr & 7) << 4)));
  };
  auto ldB = [&](int buf, int nf, int kk) -> bf16x8 {
    int row = wc * 64 + nf * 16 + lr;
    return *(const bf16x8*)((const char*)&Bsm[buf][0] + row * 128 +
                            ((kk * 64 + lg * 16) ^ ((lr & 7) << 4)));
  };

  f32x4 acc[8][4] = {};
  const int nt = K >> 6;

  // prologue: stage tile 0 into buf 0
#pragma unroll
  for (int s = 0; s < 4; s++) { stA(0, s, 0); stB(0, s, 0); }
  asm volatile("s_waitcnt vmcnt(0)" ::: "memory");
  __syncthreads();

#pragma unroll 1
  for (int t = 0; t < nt; t++) {
    const int cur = t & 1, nxt = cur ^ 1;
    const int kn = (t + 1) << 6;
    const bool pre = (t + 1 < nt);
    bf16x8 a0[4][2], a1[4][2], b0[2][2], b1[2][2];

    // ---- phase 0: read A m0-3, B n0-1; stage A0-2(t+1) ----
#pragma unroll
    for (int mf = 0; mf < 4; mf++) { a0[mf][0] = ldA(cur, mf, 0); a0[mf][1] = ldA(cur, mf, 1); }
#pragma unroll
    for (int nf = 0; nf < 2; nf++) { b0[nf][0] = ldB(cur, nf, 0); b0[nf][1] = ldB(cur, nf, 1); }
    if (pre) { stA(nxt, 0, kn); stA(nxt, 1, kn); stA(nxt, 2, kn); }
    PHASE_SYNC;
    __builtin_amdgcn_s_setprio(1);
#pragma unroll
    for (int mf = 0; mf < 4; mf++)
#pragma unroll
      for (int nf = 0; nf < 2; nf++)
#pragma unroll
        for (int kk = 0; kk < 2; kk++)
          acc[mf][nf] = __builtin_amdgcn_mfma_f32_16x16x32_bf16(a0[mf][kk], b0[nf][kk], acc[mf][nf], 0, 0, 0);
    __builtin_amdgcn_s_setprio(0);

    // ---- phase 1: read B n2-3; stage A3,B0,B1(t+1) ----
#pragma unroll
    for (int nf = 0; nf < 2; nf++) { b1[nf][0] = ldB(cur, nf + 2, 0); b1[nf][1] = ldB(cur, nf + 2, 1); }
    if (pre) { stA(nxt, 3, kn); stB(nxt, 0, kn); stB(nxt, 1, kn); }
    PHASE_SYNC;
    __builtin_amdgcn_s_setprio(1);
#pragma unroll
    for (int mf = 0; mf < 4; mf++)
#pragma unroll
      for (int nf = 0; nf < 2; nf++)
#pragma unroll
        for (int kk = 0; kk < 2; kk++)
          acc[mf][nf + 2] = __builtin_amdgcn_mfma_f32_16x16x32_bf16(a0[mf][kk], b1[nf][kk], acc[mf][nf + 2], 0, 0, 0);
    __builtin_amdgcn_s_setprio(0);

    // ---- phase 2: read A m4-7 only (b0 HELD in regs); stage B2,B3(t+1) ----
#pragma unroll
    for (int mf = 0; mf < 4; mf++) { a1[mf][0] = ldA(cur, mf + 4, 0); a1[mf][1] = ldA(cur, mf + 4, 1); }
    if (pre) { stB(nxt, 2, kn); stB(nxt, 3, kn); }
    PHASE_SYNC;
    __builtin_amdgcn_s_setprio(1);
#pragma unroll
    for (int mf = 0; mf < 4; mf++)
#pragma unroll
      for (int nf = 0; nf < 2; nf++)
#pragma unroll
        for (int kk = 0; kk < 2; kk++)
          acc[mf + 4][nf] = __builtin_amdgcn_mfma_f32_16x16x32_bf16(a1[mf][kk], b0[nf][kk], acc[mf + 4][nf], 0, 0, 0);
    __builtin_amdgcn_s_setprio(0);

    // ---- phase 3: no reads/stages; drain AFTER the MFMA cluster ----
    __builtin_amdgcn_s_setprio(1);
#pragma unroll
    for (int mf = 0; mf < 4; mf++)
#pragma unroll
      for (int nf = 0; nf < 2; nf++)
#pragma unroll
        for (int kk = 0; kk < 2; kk++)
          acc[mf + 4][nf + 2] = __builtin_amdgcn_mfma_f32_16x16x32_bf16(a1[mf][kk], b1[nf][kk], acc[mf + 4][nf + 2], 0, 0, 0);
    __builtin_amdgcn_s_setprio(0);
    asm volatile("s_waitcnt vmcnt(0)" ::: "memory");
    asm volatile("s_barrier" ::: "memory");
  }

  // ---- epilogue ----
#pragma unroll
  for (int mf = 0; mf < 8; mf++) {
    const int rowb = bm * 256 + wr * 128 + mf * 16 + lg * 4;
#pragma unroll
    for (int nf = 0; nf < 4; nf++) {
      const int col = bn * 256 + wc * 64 + nf * 16 + lr;
      if constexpr (MODE == 0) {
        float* Cf = (float*)Cq;
#pragma unroll
        for (int j = 0; j < 4; j++)
          Cf[(size_t)(rowb + j) * 2048 + col] = acc[mf][nf][j];
      } else {
        if (bn < 8) {
          bf16* Cb = (bf16*)Cq;
#pragma unroll
          for (int j = 0; j < 4; j++)
            Cb[(size_t)(rowb + j) * 2048 + col] = (bf16)acc[mf][nf][j];
        } else if (bn < 10) {
          int kcol = col - 2048;
#pragma unroll
          for (int j = 0; j < 4; j++)
            Ck[(size_t)(rowb + j) * 512 + kcol] = (bf16)acc[mf][nf][j];
        } else {
          int vcol = col - 2560;                 // 0..511
          int kv = vcol >> 7, d = vcol & 127;
          int bb = rowb >> 11, t0 = rowb & 2047;
          size_t off = ((size_t)((bb * 4 + kv) * 128 + d)) * 2048 + t0;
          ushort4_ pk;
#pragma unroll
          for (int j = 0; j < 4; j++)
            pk[j] = __builtin_bit_cast(unsigned short, (bf16)acc[mf][nf][j]);
          *(ushort4_*)(Cv + off) = pk;
        }
      }
    }
  }
}

// ---------------- RoPE + rearrange: [B*T][NH*128] -> [B][NH][T][128] ----------------
template <int LOGNH>
__global__ void k_rope(const bf16* __restrict__ in, bf16* __restrict__ out,
                       const f32x2* __restrict__ tab, float scl) {
  const int NH = 1 << LOGNH;
  int idx = blockIdx.x * 256 + threadIdx.x;
  int dq = idx & 15;                        // d0 = dq*4
  int h = (idx >> 4) & (NH - 1);
  int bt = idx >> (4 + LOGNH);
  int t = bt & 2047;
  int d0 = dq * 4;
  const bf16* pin = in + (size_t)bt * (NH * 128) + h * 128;
  bf16x4 x1 = *(const bf16x4*)(pin + d0);
  bf16x4 x2 = *(const bf16x4*)(pin + 64 + d0);
  bf16x4 o1, o2;
#pragma unroll
  for (int j = 0; j < 4; j++) {
    f32x2 cs = tab[t * 64 + d0 + j];
    float c1 = cs[0] * scl, s1 = cs[1] * scl;
    float a = (float)x1[j], c2 = (float)x2[j];
    o1[j] = (bf16)(a * c1 - c2 * s1);
    o2[j] = (bf16)(c2 * c1 + a * s1);
  }
  int b = bt >> 11;
  bf16* pout = out + (((size_t)(b << LOGNH) + h) * 2048 + t) * 128;
  *(bf16x4*)(pout + d0) = o1;
  *(bf16x4*)(pout + 64 + d0) = o2;
}

// ---------------- flash attention (causal, GQA), 32x32 MFMA, nq=2 operand reuse ----------------
// Each wave owns 64 q-rows (nq=2 x 32): every K/V fragment read feeds TWO MFMAs,
// cutting LDS ops per unit work by 36% vs the 32q/wave version (LDS was the bottleneck:
// MfmaUtil 23.5 vs VALUBusy 46 with 44 LDS ops per 24 MFMAs).
// Block: 4 waves x 64 q = 256 q. Grid 4x64 paired chunks (c, 7-c): uniform 36 tiles,
// 256 blocks = exactly 1/CU (uniform, no tail). LDS 96KB -> 1 block/CU, 1 wave/SIMD.
// K,V double-buffered; one barrier per tile (stage flies under compute). RoPE-Q fused
// into Q-load; AO == Qraw in place (reads precede writes; regions disjoint per block).
__global__ __launch_bounds__(256, 1) void k_attn(const bf16* __restrict__ Qraw,
                                                 const bf16* __restrict__ Kb,
                                                 const bf16* __restrict__ Vt,
                                                 bf16* __restrict__ AO,
                                                 const f32x2* __restrict__ tab,
                                                 float qscl) {
  __shared__ bf16 Ks[2][64 * 128];  // 32KB, [kv 64][d 128] XOR-swizzled rows
  __shared__ bf16 Vs[2][128 * 64];  // 32KB, [d 128][kv 64] XOR-swizzled rows
  __shared__ bf16 Ps[4][64 * 64];   // 32KB, per-wave P[q 64][kv 64], swizzled
  const int tid = threadIdx.x, w = tid >> 6, l = tid & 63;
  const int bh = blockIdx.y, b = bh >> 4, h = bh & 15, kvh = h >> 2;
  const int pi = blockIdx.x;        // 0..3, pairs (pi, 7-pi) of 256-q chunks
  const int l31 = l & 31, hi = l >> 5;

  const bf16* Kh = Kb + (size_t)(b * 4 + kvh) * (2048 * 128);
  const bf16* Vh = Vt + (size_t)(b * 4 + kvh) * (128 * 2048);
  char* Pw = (char*)&Ps[w][0];
  const int qsw = (l & 7) << 4;     // row swizzle ((q&7)<<4); q&7 == l&7 for both nq

  auto stage = [&](int kv0, int buf) {
#pragma unroll
    for (int i = 0; i < 4; i++) {
      int krow = w * 16 + i * 4 + (l >> 4);
      int kcb = ((l & 15) * 16) ^ ((krow & 7) << 4);
      gload16(Kh + (size_t)(kv0 + krow) * 128 + (kcb >> 1), (bf16*)&Ks[buf][0] + w * 2048 + i * 512);
      int vrow = w * 32 + i * 8 + (l >> 3);
      int vcb = ((l & 7) * 16) ^ ((vrow & 7) << 4);
      gload16(Vh + (size_t)vrow * 2048 + kv0 + (vcb >> 1), (bf16*)&Vs[buf][0] + w * 2048 + i * 512);
    }
  };

#pragma unroll 1
  for (int ph = 0; ph < 2; ph++) {
    const int q0 = (ph ? (7 - pi) : pi) * 256;
    const int nt = q0 / 64 + 4;
    const int q0w = q0 + w * 64;
    const int qg0 = q0w + l31, qg1 = q0w + 32 + l31;

    // Q load (raw) + in-register RoPE + qscl fold, for both nq halves.
    // qf[nq][kk] covers d = kk*16 + hi*8 + j; pair (kk, kk+4) = (d, d+64), lane-local.
    bf16x8 qf[2][8];
#pragma unroll
    for (int nq = 0; nq < 2; nq++) {
      const int qg = q0w + nq * 32 + l31;
      const bf16* qp = Qraw + ((size_t)(b * 2048 + qg)) * 2048 + h * 128 + hi * 8;
      const f32x2* tb = tab + qg * 64 + hi * 8;
      bf16x8 xr[8];
#pragma unroll
      for (int kk = 0; kk < 8; kk++) xr[kk] = *(const bf16x8*)(qp + kk * 16);
#pragma unroll
      for (int kk = 0; kk < 4; kk++) {
#pragma unroll
        for (int j = 0; j < 8; j++) {
          f32x2 cs = tb[kk * 16 + j];
          float a = (float)xr[kk][j], c2 = (float)xr[kk + 4][j];
          qf[nq][kk][j]     = (bf16)((a * cs[0] - c2 * cs[1]) * qscl);
          qf[nq][kk + 4][j] = (bf16)((c2 * cs[0] + a * cs[1]) * qscl);
        }
      }
    }

    f32x16 ot[2][4] = {};            // [nq][dt]: rows d = dt*32 + (r&3)+8*(r>>2)+4*hi, col q
    float m_[2] = {-3e38f, -3e38f}, l_[2] = {0.f, 0.f};

    int cur = 0;
    stage(0, 0);
    __syncthreads();

#pragma unroll 1
    for (int t = 0; t < nt; t++) {
      const int kv0 = t * 64;
      if (t + 1 < nt) stage(kv0 + 64, cur ^ 1);

      if (kv0 <= q0w + 63) {
        // S^T = K @ Q^T: st[nb][nq], kv = kv0 + nb*32 + (r&3)+8*(r>>2)+4*hi, q = nq*32+l31
        f32x16 st[2][2] = {};
        __builtin_amdgcn_s_setprio(1);
#pragma unroll
        for (int nb = 0; nb < 2; nb++) {
          const int row = nb * 32 + l31;
          const char* kbase = (const char*)&Ks[cur][0] + row * 256;
#pragma unroll
          for (int kk = 0; kk < 8; kk++) {
            bf16x8 kf = *(const bf16x8*)(kbase + ((kk * 32 + hi * 16) ^ qsw));
            st[nb][0] = __builtin_amdgcn_mfma_f32_32x32x16_bf16(kf, qf[0][kk], st[nb][0], 0, 0, 0);
            st[nb][1] = __builtin_amdgcn_mfma_f32_32x32x16_bf16(kf, qf[1][kk], st[nb][1], 0, 0, 0);
          }
        }
        __builtin_amdgcn_s_setprio(0);

        // causal mask (diag tiles only); log2 domain
        if (kv0 + 63 > q0w) {
#pragma unroll
          for (int nb = 0; nb < 2; nb++) {
            const int kvb = kv0 + nb * 32 + 4 * hi;
#pragma unroll
            for (int r = 0; r < 16; r++) {
              const int kg = kvb + (r & 3) + 8 * (r >> 2);
              if (kg > qg0) st[nb][0][r] = -3e38f;
              if (kg > qg1) st[nb][1][r] = -3e38f;
            }
          }
        }
        // row max per nq: in-lane tree + one cross-half shfl
        float mx[2];
#pragma unroll
        for (int nq = 0; nq < 2; nq++) {
          float m = -3e38f;
#pragma unroll
          for (int nb = 0; nb < 2; nb++)
#pragma unroll
            for (int r = 0; r < 16; r++) m = fmaxf(m, st[nb][nq][r]);
          m = fmaxf(m, __shfl_xor(m, 32));
          mx[nq] = m;
        }
        // defer-max (THR = 8 in log2 domain)
        if (!__all(fmaxf(mx[0] - m_[0], mx[1] - m_[1]) <= 8.f)) {
#pragma unroll
          for (int nq = 0; nq < 2; nq++) {
            float mnew = fmaxf(m_[nq], mx[nq]);
            float corr = exp2f(m_[nq] - mnew);
            m_[nq] = mnew; l_[nq] *= corr;
#pragma unroll
            for (int dt = 0; dt < 4; dt++)
#pragma unroll
              for (int r = 0; r < 16; r++) ot[nq][dt][r] *= corr;
          }
        }
        // P = exp2(s - m), row-sum; write P[q][kv] pairs to per-wave LDS (8B swizzled)
#pragma unroll
        for (int nq = 0; nq < 2; nq++) {
          float ls = 0.f;
          const int qloc = nq * 32 + l31;
#pragma unroll
          for (int nb = 0; nb < 2; nb++)
#pragma unroll
            for (int a = 0; a < 4; a++) {
              uint2_ pr;
#pragma unroll
              for (int half = 0; half < 2; half++) {
                float p0 = exp2f(st[nb][nq][4 * a + 2 * half] - m_[nq]);
                float p1 = exp2f(st[nb][nq][4 * a + 2 * half + 1] - m_[nq]);
                ls += p0 + p1;
                unsigned short b0 = __builtin_bit_cast(unsigned short, (bf16)p0);
                unsigned short b1 = __builtin_bit_cast(unsigned short, (bf16)p1);
                pr[half] = (unsigned int)b0 | ((unsigned int)b1 << 16);
              }
              *(uint2_*)(Pw + qloc * 128 + ((nb * 64 + a * 16 + hi * 8) ^ qsw)) = pr;
            }
          ls += __shfl_xor(ls, 32);
          l_[nq] += ls;
        }

        // O^T += V^T @ P^T: each vf read feeds both nq MFMAs
        __builtin_amdgcn_s_setprio(1);
#pragma unroll
        for (int kb = 0; kb < 4; kb++) {
          bf16x8 pb[2];
#pragma unroll
          for (int nq = 0; nq < 2; nq++)
            pb[nq] = *(const bf16x8*)(Pw + (nq * 32 + l31) * 128 + ((kb * 32 + hi * 16) ^ qsw));
#pragma unroll
          for (int dt = 0; dt < 4; dt++) {
            const int vrow = dt * 32 + l31;
            const char* vp = (const char*)&Vs[cur][0] + vrow * 128 + ((kb * 32 + hi * 16) ^ qsw);
            bf16x8 vf = *(const bf16x8*)vp;
            ot[0][dt] = __builtin_amdgcn_mfma_f32_32x32x16_bf16(vf, pb[0], ot[0][dt], 0, 0, 0);
            ot[1][dt] = __builtin_amdgcn_mfma_f32_32x32x16_bf16(vf, pb[1], ot[1][dt], 0, 0, 0);
          }
        }
        __builtin_amdgcn_s_setprio(0);
      }

      __syncthreads();   // one barrier/tile: drains stage(t+1) (flew under compute),
                         // aligns all waves before cur-buffer overwrite
      cur ^= 1;
    }

    // epilogue: O^T / l -> AO[b*T + q][h*128 + d]
#pragma unroll
    for (int nq = 0; nq < 2; nq++) {
      const float inv = 1.f / l_[nq];
      const int qg = q0w + nq * 32 + l31;
      bf16* op = AO + ((size_t)b * 2048 + qg) * 2048 + h * 128;
#pragma unroll
      for (int dt = 0; dt < 4; dt++)
#pragma unroll
        for (int rq = 0; rq < 4; rq++) {
          ushort4_ pk;
#pragma unroll
          for (int j = 0; j < 4; j++)
            pk[j] = __builtin_bit_cast(unsigned short, (bf16)(ot[nq][dt][rq * 4 + j] * inv));
          *(ushort4_*)(op + dt * 32 + rq * 8 + hi * 4) = pk;
        }
    }
  }
}

// ---------------- launch ----------------
extern "C" void kernel_launch(void* const* d_in, const int* in_sizes, int n_in,
                              void* d_out, int out_size, void* d_ws, size_t ws_size,
                              hipStream_t stream) {
  const float* x  = (const float*)d_in[0];
  // d_in[1] = additive causal mask: implemented analytically, not read
  const float* wq = (const float*)d_in[2];
  const float* wk = (const float*)d_in[3];
  const float* wv = (const float*)d_in[4];
  const float* wo = (const float*)d_in[5];

  char* p = (char*)d_ws;
  auto alloc = [&](size_t bytes) { char* r = p; p += (bytes + 255) & ~(size_t)255; return r; };
  bf16*  xb     = (bf16*)alloc(8192ull * 2048 * 2);
  bf16*  wqkvT  = (bf16*)alloc(3072ull * 2048 * 2);   // rows: 0-2047 wq^T, 2048-2559 wk^T, 2560-3071 wv^T
  bf16*  woT    = (bf16*)alloc(2048ull * 2048 * 2);
  f32x2* tab    = (f32x2*)alloc(2048ull * 64 * 8);
  bf16*  Qtmp   = (bf16*)alloc(8192ull * 2048 * 2);   // raw Q; attention writes AO in place
  bf16*  Ktmp   = (bf16*)alloc(8192ull * 512 * 2);
  bf16*  Kr     = (bf16*)alloc(8192ull * 512 * 2);
  bf16*  Vr     = (bf16*)alloc(8192ull * 512 * 2);

  k_cvt<<<16384, 256, 0, stream>>>(x, xb);
  k_transpose_cvt<<<dim3(32, 32), 256, 0, stream>>>(wq, wqkvT, 2048, 2048);
  k_transpose_cvt<<<dim3(8, 32),  256, 0, stream>>>(wk, wqkvT + 2048ull * 2048, 2048, 512);
  k_transpose_cvt<<<dim3(8, 32),  256, 0, stream>>>(wv, wqkvT + 2560ull * 2048, 2048, 512);
  k_transpose_cvt<<<dim3(32, 32), 256, 0, stream>>>(wo, woT, 2048, 2048);
  k_rope_tab<<<512, 256, 0, stream>>>(tab);

  // fused QKV projection: [8192 x 2048] @ [3072 x 2048]^T
  k_gemm256<1><<<dim3(12, 32), 512, 0, stream>>>(xb, wqkvT, Qtmp, Ktmp, Vr, 2048);

  const float qscl = 0.08838834764831845f * 1.4426950408889634f;  // scale * log2(e)
  k_rope<2><<<2048, 256, 0, stream>>>(Ktmp, Kr, tab, 1.0f);  // K: 4 kv heads

  // attention: RoPE-Q fused into Q-load; AO written in place over Qtmp
  k_attn<<<dim3(4, 64), 256, 0, stream>>>(Qtmp, Kr, Vr, Qtmp, tab, qscl);

  // output projection: [8192 x 2048] @ [2048 x 2048]^T -> fp32
  k_gemm256<0><<<dim3(8, 32), 512, 0, stream>>>(Qtmp, woT, d_out, nullptr, nullptr, 2048);
}

// Round 12
// 331.392 us; speedup vs baseline: 1.1777x; 1.1777x over previous
//
#include <hip/hip_runtime.h>

typedef __bf16 bf16;
typedef float  f32x4  __attribute__((ext_vector_type(4)));
typedef float  f32x2  __attribute__((ext_vector_type(2)));
typedef float  f32x16 __attribute__((ext_vector_type(16)));
typedef __bf16 bf16x8 __attribute__((ext_vector_type(8)));
typedef __bf16 bf16x4 __attribute__((ext_vector_type(4)));
typedef unsigned short ushort4_ __attribute__((ext_vector_type(4)));
typedef unsigned int   uint2_   __attribute__((ext_vector_type(2)));

typedef unsigned int __attribute__((address_space(1))) uint_g;
typedef unsigned int __attribute__((address_space(3))) uint_l;

#define DEV __device__ __forceinline__

DEV void gload16(const void* g, void* l) {
  // async global->LDS, 16B per lane; LDS dst is wave-uniform base + lane*16
  __builtin_amdgcn_global_load_lds((uint_g*)g, (uint_l*)l, 16, 0, 0);
}

#define PHASE_SYNC do { \
  asm volatile("s_barrier" ::: "memory"); \
  asm volatile("s_waitcnt lgkmcnt(0)" ::: "memory"); \
  __builtin_amdgcn_sched_barrier(0); } while (0)

// ---------------- fp32 -> bf16 convert (vectorized) ----------------
__global__ void k_cvt(const float* __restrict__ in, bf16* __restrict__ out) {
  int i = blockIdx.x * 256 + threadIdx.x;          // one float4 per thread
  f32x4 v = *((const f32x4*)in + i);
  bf16x4 o;
  o[0] = (bf16)v[0]; o[1] = (bf16)v[1]; o[2] = (bf16)v[2]; o[3] = (bf16)v[3];
  *((bf16x4*)out + i) = o;
}

// ---------------- [K][N] fp32 -> [N][K] bf16 transpose ----------------
__global__ void k_transpose_cvt(const float* __restrict__ in, bf16* __restrict__ out,
                                int K, int N) {
  __shared__ bf16 tile[64][65];
  int n0 = blockIdx.x * 64, k0 = blockIdx.y * 64;
  int tx = threadIdx.x & 63, ty = threadIdx.x >> 6;
#pragma unroll
  for (int r = 0; r < 64; r += 4)
    tile[r + ty][tx] = (bf16)in[(size_t)(k0 + r + ty) * N + n0 + tx];
  __syncthreads();
#pragma unroll
  for (int r = 0; r < 64; r += 4)
    out[(size_t)(n0 + r + ty) * K + k0 + tx] = tile[tx][r + ty];
}

// ---------------- RoPE cos/sin table: [T][64] of (cos,sin) ----------------
__global__ void k_rope_tab(f32x2* __restrict__ tab) {
  int idx = blockIdx.x * 256 + threadIdx.x;   // T*64
  int t = idx >> 6, i = idx & 63;
  float inv = powf(10000.f, -(float)i * (1.f / 64.f));
  float ang = (float)t * inv;
  f32x2 cs; cs[0] = cosf(ang); cs[1] = sinf(ang);
  tab[idx] = cs;
}

// ---------------- 256x256 GEMM (R8 schedule), used for the output projection ----------------
__global__ __launch_bounds__(512, 1) void k_gemm256(const bf16* __restrict__ A,
                                                    const bf16* __restrict__ Bt,
                                                    float* __restrict__ C,
                                                    int K) {
  __shared__ bf16 Asm[2][256 * 64];
  __shared__ bf16 Bsm[2][256 * 64];
  const int tid = threadIdx.x;
  const int w = tid >> 6, l = tid & 63, lr = l & 15, lg = l >> 4;
  const int wr = w >> 2, wc = w & 3;
  const int bn = blockIdx.x, bm = blockIdx.y;

  const int srow = tid >> 3;                                    // 0..63
  const int scb = ((tid & 7) << 4) ^ ((srow & 7) << 4);         // pre-swizzled col byte
  const bf16* Ag = A  + ((size_t)(bm * 256) + srow) * K;
  const bf16* Bg = Bt + ((size_t)(bn * 256) + srow) * K;
  const int ldsbase = w << 10;                                  // per-wave 1KB slice

  auto stA = [&](int buf, int s, int k0) {
    gload16((const char*)Ag + ((size_t)(s * 64) * K + k0) * 2 + scb,
            (char*)&Asm[buf][0] + s * 8192 + ldsbase);
  };
  auto stB = [&](int buf, int s, int k0) {
    gload16((const char*)Bg + ((size_t)(s * 64) * K + k0) * 2 + scb,
            (char*)&Bsm[buf][0] + s * 8192 + ldsbase);
  };
  auto ldA = [&](int buf, int mf, int kk) -> bf16x8 {
    int row = wr * 128 + mf * 16 + lr;
    return *(const bf16x8*)((const char*)&Asm[buf][0] + row * 128 +
                            ((kk * 64 + lg * 16) ^ ((lr & 7) << 4)));
  };
  auto ldB = [&](int buf, int nf, int kk) -> bf16x8 {
    int row = wc * 64 + nf * 16 + lr;
    return *(const bf16x8*)((const char*)&Bsm[buf][0] + row * 128 +
                            ((kk * 64 + lg * 16) ^ ((lr & 7) << 4)));
  };

  f32x4 acc[8][4] = {};
  const int nt = K >> 6;

#pragma unroll
  for (int s = 0; s < 4; s++) { stA(0, s, 0); stB(0, s, 0); }
  asm volatile("s_waitcnt vmcnt(0)" ::: "memory");
  __syncthreads();

#pragma unroll 1
  for (int t = 0; t < nt; t++) {
    const int cur = t & 1, nxt = cur ^ 1;
    const int kn = (t + 1) << 6;
    const bool pre = (t + 1 < nt);
    bf16x8 a0[4][2], a1[4][2], b0[2][2], b1[2][2];

    // ---- phase 0: read A m0-3, B n0-1; stage A0-2(t+1) ----
#pragma unroll
    for (int mf = 0; mf < 4; mf++) { a0[mf][0] = ldA(cur, mf, 0); a0[mf][1] = ldA(cur, mf, 1); }
#pragma unroll
    for (int nf = 0; nf < 2; nf++) { b0[nf][0] = ldB(cur, nf, 0); b0[nf][1] = ldB(cur, nf, 1); }
    if (pre) { stA(nxt, 0, kn); stA(nxt, 1, kn); stA(nxt, 2, kn); }
    PHASE_SYNC;
    __builtin_amdgcn_s_setprio(1);
#pragma unroll
    for (int mf = 0; mf < 4; mf++)
#pragma unroll
      for (int nf = 0; nf < 2; nf++)
#pragma unroll
        for (int kk = 0; kk < 2; kk++)
          acc[mf][nf] = __builtin_amdgcn_mfma_f32_16x16x32_bf16(a0[mf][kk], b0[nf][kk], acc[mf][nf], 0, 0, 0);
    __builtin_amdgcn_s_setprio(0);

    // ---- phase 1: read B n2-3; stage A3,B0,B1(t+1) ----
#pragma unroll
    for (int nf = 0; nf < 2; nf++) { b1[nf][0] = ldB(cur, nf + 2, 0); b1[nf][1] = ldB(cur, nf + 2, 1); }
    if (pre) { stA(nxt, 3, kn); stB(nxt, 0, kn); stB(nxt, 1, kn); }
    PHASE_SYNC;
    __builtin_amdgcn_s_setprio(1);
#pragma unroll
    for (int mf = 0; mf < 4; mf++)
#pragma unroll
      for (int nf = 0; nf < 2; nf++)
#pragma unroll
        for (int kk = 0; kk < 2; kk++)
          acc[mf][nf + 2] = __builtin_amdgcn_mfma_f32_16x16x32_bf16(a0[mf][kk], b1[nf][kk], acc[mf][nf + 2], 0, 0, 0);
    __builtin_amdgcn_s_setprio(0);

    // ---- phase 2: read A m4-7 only (b0 held in regs); stage B2,B3(t+1) ----
#pragma unroll
    for (int mf = 0; mf < 4; mf++) { a1[mf][0] = ldA(cur, mf + 4, 0); a1[mf][1] = ldA(cur, mf + 4, 1); }
    if (pre) { stB(nxt, 2, kn); stB(nxt, 3, kn); }
    PHASE_SYNC;
    __builtin_amdgcn_s_setprio(1);
#pragma unroll
    for (int mf = 0; mf < 4; mf++)
#pragma unroll
      for (int nf = 0; nf < 2; nf++)
#pragma unroll
        for (int kk = 0; kk < 2; kk++)
          acc[mf + 4][nf] = __builtin_amdgcn_mfma_f32_16x16x32_bf16(a1[mf][kk], b0[nf][kk], acc[mf + 4][nf], 0, 0, 0);
    __builtin_amdgcn_s_setprio(0);

    // ---- phase 3: no reads/stages; drain AFTER the MFMA cluster ----
    __builtin_amdgcn_s_setprio(1);
#pragma unroll
    for (int mf = 0; mf < 4; mf++)
#pragma unroll
      for (int nf = 0; nf < 2; nf++)
#pragma unroll
        for (int kk = 0; kk < 2; kk++)
          acc[mf + 4][nf + 2] = __builtin_amdgcn_mfma_f32_16x16x32_bf16(a1[mf][kk], b1[nf][kk], acc[mf + 4][nf + 2], 0, 0, 0);
    __builtin_amdgcn_s_setprio(0);
    asm volatile("s_waitcnt vmcnt(0)" ::: "memory");
    asm volatile("s_barrier" ::: "memory");
  }

#pragma unroll
  for (int mf = 0; mf < 8; mf++) {
    const int rowb = bm * 256 + wr * 128 + mf * 16 + lg * 4;
#pragma unroll
    for (int nf = 0; nf < 4; nf++) {
      const int col = bn * 256 + wc * 64 + nf * 16 + lr;
#pragma unroll
      for (int j = 0; j < 4; j++)
        C[(size_t)(rowb + j) * 2048 + col] = acc[mf][nf][j];
    }
  }
}

// ---------------- 256x192 QKV GEMM (tail-exact grid: 16x32 = 512 blocks = 2.0 rounds) ----------------
// Same R8 schedule shape: 4 phases (16/8/16/8 MFMA), stages issued P0-P2, b-frags held,
// single vmcnt(0)+barrier drain at P3 end.  LDS 112KB (A 64 + B 48), 1 block/CU.
// Epilogue col split (per 16-col tile, lane-invariant): <2048 Q bf16, <2560 K bf16, else V^T.
__global__ __launch_bounds__(512, 1) void k_gemmQKV(const bf16* __restrict__ A,
                                                    const bf16* __restrict__ Bt,
                                                    bf16* __restrict__ Cq,
                                                    bf16* __restrict__ Ck,
                                                    bf16* __restrict__ Cv,
                                                    int K) {
  __shared__ bf16 Asm[2][256 * 64];
  __shared__ bf16 Bsm[2][192 * 64];
  const int tid = threadIdx.x;
  const int w = tid >> 6, l = tid & 63, lr = l & 15, lg = l >> 4;
  const int wr = w >> 2, wc = w & 3;
  const int bn = blockIdx.x, bm = blockIdx.y;

  const int srow = tid >> 3;                                    // 0..63
  const int scb = ((tid & 7) << 4) ^ ((srow & 7) << 4);         // pre-swizzled col byte
  const bf16* Ag = A  + ((size_t)(bm * 256) + srow) * K;
  const bf16* Bg = Bt + ((size_t)(bn * 192) + srow) * K;
  const int ldsbase = w << 10;                                  // per-wave 1KB slice

  auto stA = [&](int buf, int s, int k0) {
    gload16((const char*)Ag + ((size_t)(s * 64) * K + k0) * 2 + scb,
            (char*)&Asm[buf][0] + s * 8192 + ldsbase);
  };
  auto stB = [&](int buf, int s, int k0) {
    gload16((const char*)Bg + ((size_t)(s * 64) * K + k0) * 2 + scb,
            (char*)&Bsm[buf][0] + s * 8192 + ldsbase);
  };
  auto ldA = [&](int buf, int mf, int kk) -> bf16x8 {
    int row = wr * 128 + mf * 16 + lr;
    return *(const bf16x8*)((const char*)&Asm[buf][0] + row * 128 +
                            ((kk * 64 + lg * 16) ^ ((lr & 7) << 4)));
  };
  auto ldB = [&](int buf, int nf, int kk) -> bf16x8 {
    int row = wc * 48 + nf * 16 + lr;
    return *(const bf16x8*)((const char*)&Bsm[buf][0] + row * 128 +
                            ((kk * 64 + lg * 16) ^ ((lr & 7) << 4)));
  };

  f32x4 acc[8][3] = {};
  const int nt = K >> 6;

  // prologue: stage tile 0 (A 4 units + B 3 units), drain, sync
#pragma unroll
  for (int s = 0; s < 4; s++) stA(0, s, 0);
#pragma unroll
  for (int s = 0; s < 3; s++) stB(0, s, 0);
  asm volatile("s_waitcnt vmcnt(0)" ::: "memory");
  __syncthreads();

#pragma unroll 1
  for (int t = 0; t < nt; t++) {
    const int cur = t & 1, nxt = cur ^ 1;
    const int kn = (t + 1) << 6;
    const bool pre = (t + 1 < nt);
    bf16x8 a0[4][2], a1[4][2], b01[2][2], b2[2];

    // ---- phase 0: read A m0-3 (2kk), B n0-1 (2kk); stage A0,A1,A2(t+1); 16 MFMA ----
#pragma unroll
    for (int mf = 0; mf < 4; mf++) { a0[mf][0] = ldA(cur, mf, 0); a0[mf][1] = ldA(cur, mf, 1); }
#pragma unroll
    for (int nf = 0; nf < 2; nf++) { b01[nf][0] = ldB(cur, nf, 0); b01[nf][1] = ldB(cur, nf, 1); }
    if (pre) { stA(nxt, 0, kn); stA(nxt, 1, kn); stA(nxt, 2, kn); }
    PHASE_SYNC;
    __builtin_amdgcn_s_setprio(1);
#pragma unroll
    for (int mf = 0; mf < 4; mf++)
#pragma unroll
      for (int nf = 0; nf < 2; nf++)
#pragma unroll
        for (int kk = 0; kk < 2; kk++)
          acc[mf][nf] = __builtin_amdgcn_mfma_f32_16x16x32_bf16(a0[mf][kk], b01[nf][kk], acc[mf][nf], 0, 0, 0);
    __builtin_amdgcn_s_setprio(0);

    // ---- phase 1: read B n2 (2kk); stage A3,B0(t+1); 8 MFMA ----
    b2[0] = ldB(cur, 2, 0); b2[1] = ldB(cur, 2, 1);
    if (pre) { stA(nxt, 3, kn); stB(nxt, 0, kn); }
    PHASE_SYNC;
    __builtin_amdgcn_s_setprio(1);
#pragma unroll
    for (int mf = 0; mf < 4; mf++)
#pragma unroll
      for (int kk = 0; kk < 2; kk++)
        acc[mf][2] = __builtin_amdgcn_mfma_f32_16x16x32_bf16(a0[mf][kk], b2[kk], acc[mf][2], 0, 0, 0);
    __builtin_amdgcn_s_setprio(0);

    // ---- phase 2: read A m4-7 (2kk) (b01 held); stage B1,B2(t+1); 16 MFMA ----
#pragma unroll
    for (int mf = 0; mf < 4; mf++) { a1[mf][0] = ldA(cur, mf + 4, 0); a1[mf][1] = ldA(cur, mf + 4, 1); }
    if (pre) { stB(nxt, 1, kn); stB(nxt, 2, kn); }
    PHASE_SYNC;
    __builtin_amdgcn_s_setprio(1);
#pragma unroll
    for (int mf = 0; mf < 4; mf++)
#pragma unroll
      for (int nf = 0; nf < 2; nf++)
#pragma unroll
        for (int kk = 0; kk < 2; kk++)
          acc[mf + 4][nf] = __builtin_amdgcn_mfma_f32_16x16x32_bf16(a1[mf][kk], b01[nf][kk], acc[mf + 4][nf], 0, 0, 0);
    __builtin_amdgcn_s_setprio(0);

    // ---- phase 3: no reads/stages; 8 MFMA; drain AFTER ----
    __builtin_amdgcn_s_setprio(1);
#pragma unroll
    for (int mf = 0; mf < 4; mf++)
#pragma unroll
      for (int kk = 0; kk < 2; kk++)
        acc[mf + 4][2] = __builtin_amdgcn_mfma_f32_16x16x32_bf16(a1[mf][kk], b2[kk], acc[mf + 4][2], 0, 0, 0);
    __builtin_amdgcn_s_setprio(0);
    asm volatile("s_waitcnt vmcnt(0)" ::: "memory");
    asm volatile("s_barrier" ::: "memory");
  }

  // ---- epilogue: per-16-col-tile region split (boundaries 2048/2560 are x16) ----
#pragma unroll
  for (int mf = 0; mf < 8; mf++) {
    const int rowb = bm * 256 + wr * 128 + mf * 16 + lg * 4;
#pragma unroll
    for (int nf = 0; nf < 3; nf++) {
      const int c0 = bn * 192 + wc * 48 + nf * 16;   // lane-invariant tile base
      const int col = c0 + lr;
      if (c0 < 2048) {
#pragma unroll
        for (int j = 0; j < 4; j++)
          Cq[(size_t)(rowb + j) * 2048 + col] = (bf16)acc[mf][nf][j];
      } else if (c0 < 2560) {
        const int kcol = col - 2048;
#pragma unroll
        for (int j = 0; j < 4; j++)
          Ck[(size_t)(rowb + j) * 512 + kcol] = (bf16)acc[mf][nf][j];
      } else {
        const int vcol = col - 2560;                 // 0..511
        const int kv = vcol >> 7, d = vcol & 127;
        const int bb = rowb >> 11, t0 = rowb & 2047;
        const size_t off = ((size_t)((bb * 4 + kv) * 128 + d)) * 2048 + t0;
        ushort4_ pk;
#pragma unroll
        for (int j = 0; j < 4; j++)
          pk[j] = __builtin_bit_cast(unsigned short, (bf16)acc[mf][nf][j]);
        *(ushort4_*)(Cv + off) = pk;
      }
    }
  }
}

// ---------------- RoPE + rearrange: [B*T][NH*128] -> [B][NH][T][128] ----------------
template <int LOGNH>
__global__ void k_rope(const bf16* __restrict__ in, bf16* __restrict__ out,
                       const f32x2* __restrict__ tab, float scl) {
  const int NH = 1 << LOGNH;
  int idx = blockIdx.x * 256 + threadIdx.x;
  int dq = idx & 15;                        // d0 = dq*4
  int h = (idx >> 4) & (NH - 1);
  int bt = idx >> (4 + LOGNH);
  int t = bt & 2047;
  int d0 = dq * 4;
  const bf16* pin = in + (size_t)bt * (NH * 128) + h * 128;
  bf16x4 x1 = *(const bf16x4*)(pin + d0);
  bf16x4 x2 = *(const bf16x4*)(pin + 64 + d0);
  bf16x4 o1, o2;
#pragma unroll
  for (int j = 0; j < 4; j++) {
    f32x2 cs = tab[t * 64 + d0 + j];
    float c1 = cs[0] * scl, s1 = cs[1] * scl;
    float a = (float)x1[j], c2 = (float)x2[j];
    o1[j] = (bf16)(a * c1 - c2 * s1);
    o2[j] = (bf16)(c2 * c1 + a * s1);
  }
  int b = bt >> 11;
  bf16* pout = out + (((size_t)(b << LOGNH) + h) * 2048 + t) * 128;
  *(bf16x4*)(pout + d0) = o1;
  *(bf16x4*)(pout + 64 + d0) = o2;
}

// ---------------- flash attention (causal, GQA), 32x32 MFMA, pipelined dbuf ----------------
// R8 version (best measured): 4 waves x 32 q-rows, paired blocks, K/V dbuf, one barrier
// per tile, RoPE-Q fused into Q-load, AO == Qraw in place.
__global__ __launch_bounds__(256, 2) void k_attn(const bf16* __restrict__ Qraw,
                                                 const bf16* __restrict__ Kb,
                                                 const bf16* __restrict__ Vt,
                                                 bf16* __restrict__ AO,
                                                 const f32x2* __restrict__ tab,
                                                 float qscl) {
  __shared__ bf16 Ks[2][64 * 128];  // 32KB, [kv 64][d 128] XOR-swizzled rows
  __shared__ bf16 Vs[2][128 * 64];  // 32KB, [d 128][kv 64] XOR-swizzled rows
  __shared__ bf16 Ps[4][32 * 64];   // 16KB, per-wave P[q 32][kv 64], swizzled
  const int tid = threadIdx.x, w = tid >> 6, l = tid & 63;
  const int bh = blockIdx.y, b = bh >> 4, h = bh & 15, kvh = h >> 2;
  const int pi = blockIdx.x;
  const int l31 = l & 31, hi = l >> 5;

  const bf16* Kh = Kb + (size_t)(b * 4 + kvh) * (2048 * 128);
  const bf16* Vh = Vt + (size_t)(b * 4 + kvh) * (128 * 2048);
  char* Pw = (char*)&Ps[w][0] + l31 * 128;   // this lane's q-row in the per-wave P tile
  const int qsw = (l & 7) << 4;              // row swizzle (q & 7) << 4

  auto stage = [&](int kv0, int buf) {
#pragma unroll
    for (int i = 0; i < 4; i++) {
      int krow = w * 16 + i * 4 + (l >> 4);
      int kcb = ((l & 15) * 16) ^ ((krow & 7) << 4);
      gload16(Kh + (size_t)(kv0 + krow) * 128 + (kcb >> 1), (bf16*)&Ks[buf][0] + w * 2048 + i * 512);
      int vrow = w * 32 + i * 8 + (l >> 3);
      int vcb = ((l & 7) * 16) ^ ((vrow & 7) << 4);
      gload16(Vh + (size_t)vrow * 2048 + kv0 + (vcb >> 1), (bf16*)&Vs[buf][0] + w * 2048 + i * 512);
    }
  };

#pragma unroll 1
  for (int ph = 0; ph < 2; ph++) {
    const int q0 = (ph ? (15 - pi) : pi) * 128;
    const int nt = q0 / 64 + 2;
    const int qw0 = q0 + w * 32;
    const int qg = qw0 + l31;

    // Q load (raw) + in-register RoPE + qscl fold:
    // qf[kk] covers d = kk*16 + hi*8 + j; pair (kk, kk+4) = (d, d+64), lane-local.
    bf16x8 qf[8];
    {
      const bf16* qp = Qraw + ((size_t)(b * 2048 + qg)) * 2048 + h * 128 + hi * 8;
      const f32x2* tb = tab + qg * 64 + hi * 8;
      bf16x8 xr[8];
#pragma unroll
      for (int kk = 0; kk < 8; kk++) xr[kk] = *(const bf16x8*)(qp + kk * 16);
#pragma unroll
      for (int kk = 0; kk < 4; kk++) {
#pragma unroll
        for (int j = 0; j < 8; j++) {
          f32x2 cs = tb[kk * 16 + j];
          float a = (float)xr[kk][j], c2 = (float)xr[kk + 4][j];
          qf[kk][j]     = (bf16)((a * cs[0] - c2 * cs[1]) * qscl);
          qf[kk + 4][j] = (bf16)((c2 * cs[0] + a * cs[1]) * qscl);
        }
      }
    }

    f32x16 ot[4] = {};               // O^T rows d = dt*32 + (r&3)+8*(r>>2)+4*hi, col q = l&31
    float m_ = -3e38f, l_ = 0.f;

    int cur = 0;
    stage(0, 0);
    __syncthreads();

#pragma unroll 1
    for (int t = 0; t < nt; t++) {
      const int kv0 = t * 64;
      if (t + 1 < nt) stage(kv0 + 64, cur ^ 1);

      if (kv0 <= qw0 + 31) {
        // S^T = K @ Q^T: st[nb], rows kv = kv0 + nb*32 + (r&3)+8*(r>>2)+4*hi, col q = l&31
        f32x16 st[2] = {};
        __builtin_amdgcn_s_setprio(1);
#pragma unroll
        for (int nb = 0; nb < 2; nb++) {
          const int row = nb * 32 + l31;
          const char* kbase = (const char*)&Ks[cur][0] + row * 256;
#pragma unroll
          for (int kk = 0; kk < 8; kk++) {
            bf16x8 kf = *(const bf16x8*)(kbase + ((kk * 32 + hi * 16) ^ qsw));
            st[nb] = __builtin_amdgcn_mfma_f32_32x32x16_bf16(kf, qf[kk], st[nb], 0, 0, 0);
          }
        }
        __builtin_amdgcn_s_setprio(0);

        // causal mask (diag tiles only); values already in log2 domain
        if (kv0 + 63 > qw0) {
#pragma unroll
          for (int nb = 0; nb < 2; nb++) {
            const int kvb = kv0 + nb * 32 + 4 * hi;
#pragma unroll
            for (int r = 0; r < 16; r++) {
              int kg = kvb + (r & 3) + 8 * (r >> 2);
              if (kg > qg) st[nb][r] = -3e38f;
            }
          }
        }
        // row max: in-lane tree + one cross-half shfl
        float mx = -3e38f;
#pragma unroll
        for (int nb = 0; nb < 2; nb++)
#pragma unroll
          for (int r = 0; r < 16; r++) mx = fmaxf(mx, st[nb][r]);
        mx = fmaxf(mx, __shfl_xor(mx, 32));
        // defer-max (THR = 8 in log2 domain)
        if (!__all(mx - m_ <= 8.f)) {
          float mnew = fmaxf(m_, mx);
          float corr = exp2f(m_ - mnew);
          m_ = mnew; l_ *= corr;
#pragma unroll
          for (int dt = 0; dt < 4; dt++)
#pragma unroll
            for (int r = 0; r < 16; r++) ot[dt][r] *= corr;
        }
        // P = exp2(s - m), row-sum; write P[q][kv] pairs to per-wave LDS (8B swizzled stores)
        float ls = 0.f;
#pragma unroll
        for (int nb = 0; nb < 2; nb++)
#pragma unroll
          for (int a = 0; a < 4; a++) {
            uint2_ pr;
#pragma unroll
            for (int half = 0; half < 2; half++) {
              float p0 = exp2f(st[nb][4 * a + 2 * half] - m_);
              float p1 = exp2f(st[nb][4 * a + 2 * half + 1] - m_);
              ls += p0 + p1;
              unsigned short b0 = __builtin_bit_cast(unsigned short, (bf16)p0);
              unsigned short b1 = __builtin_bit_cast(unsigned short, (bf16)p1);
              pr[half] = (unsigned int)b0 | ((unsigned int)b1 << 16);
            }
            *(uint2_*)(Pw + ((nb * 64 + a * 16 + hi * 8) ^ qsw)) = pr;
          }
        ls += __shfl_xor(ls, 32);
        l_ += ls;

        // O^T += V^T @ P^T  (B-frag read back: elem j = P[q][kb*16 + 8*hi + j])
        __builtin_amdgcn_s_setprio(1);
#pragma unroll
        for (int kb = 0; kb < 4; kb++) {
          bf16x8 pb = *(const bf16x8*)(Pw + ((kb * 32 + hi * 16) ^ qsw));
#pragma unroll
          for (int dt = 0; dt < 4; dt++) {
            const int vrow = dt * 32 + l31;
            const char* vp = (const char*)&Vs[cur][0] + vrow * 128 + ((kb * 32 + hi * 16) ^ qsw);
            bf16x8 vf = *(const bf16x8*)vp;
            ot[dt] = __builtin_amdgcn_mfma_f32_32x32x16_bf16(vf, pb, ot[dt], 0, 0, 0);
          }
        }
        __builtin_amdgcn_s_setprio(0);
      }

      __syncthreads();   // one barrier/tile: drains this wave's stage(t+1) (flew under
                         // compute) and aligns all waves before cur-buffer overwrite
      cur ^= 1;
    }

    // epilogue: O^T / l -> AO[b*T + q][h*128 + d]
    const float inv = 1.f / l_;
    bf16* op = AO + ((size_t)b * 2048 + qg) * 2048 + h * 128;
#pragma unroll
    for (int dt = 0; dt < 4; dt++)
#pragma unroll
      for (int rq = 0; rq < 4; rq++) {
        ushort4_ pk;
#pragma unroll
        for (int j = 0; j < 4; j++)
          pk[j] = __builtin_bit_cast(unsigned short, (bf16)(ot[dt][rq * 4 + j] * inv));
        *(ushort4_*)(op + dt * 32 + rq * 8 + hi * 4) = pk;
      }
  }
}

// ---------------- launch ----------------
extern "C" void kernel_launch(void* const* d_in, const int* in_sizes, int n_in,
                              void* d_out, int out_size, void* d_ws, size_t ws_size,
                              hipStream_t stream) {
  const float* x  = (const float*)d_in[0];
  // d_in[1] = additive causal mask: implemented analytically, not read
  const float* wq = (const float*)d_in[2];
  const float* wk = (const float*)d_in[3];
  const float* wv = (const float*)d_in[4];
  const float* wo = (const float*)d_in[5];

  char* p = (char*)d_ws;
  auto alloc = [&](size_t bytes) { char* r = p; p += (bytes + 255) & ~(size_t)255; return r; };
  bf16*  xb     = (bf16*)alloc(8192ull * 2048 * 2);
  bf16*  wqkvT  = (bf16*)alloc(3072ull * 2048 * 2);   // rows: 0-2047 wq^T, 2048-2559 wk^T, 2560-3071 wv^T
  bf16*  woT    = (bf16*)alloc(2048ull * 2048 * 2);
  f32x2* tab    = (f32x2*)alloc(2048ull * 64 * 8);
  bf16*  Qtmp   = (bf16*)alloc(8192ull * 2048 * 2);   // raw Q; attention writes AO in place
  bf16*  Ktmp   = (bf16*)alloc(8192ull * 512 * 2);
  bf16*  Kr     = (bf16*)alloc(8192ull * 512 * 2);
  bf16*  Vr     = (bf16*)alloc(8192ull * 512 * 2);

  k_cvt<<<16384, 256, 0, stream>>>(x, xb);
  k_transpose_cvt<<<dim3(32, 32), 256, 0, stream>>>(wq, wqkvT, 2048, 2048);
  k_transpose_cvt<<<dim3(8, 32),  256, 0, stream>>>(wk, wqkvT + 2048ull * 2048, 2048, 512);
  k_transpose_cvt<<<dim3(8, 32),  256, 0, stream>>>(wv, wqkvT + 2560ull * 2048, 2048, 512);
  k_transpose_cvt<<<dim3(32, 32), 256, 0, stream>>>(wo, woT, 2048, 2048);
  k_rope_tab<<<512, 256, 0, stream>>>(tab);

  // fused QKV projection: [8192 x 2048] @ [3072 x 2048]^T, 256x192 tiles, 512 blocks = 2.0 rounds
  k_gemmQKV<<<dim3(16, 32), 512, 0, stream>>>(xb, wqkvT, Qtmp, Ktmp, Vr, 2048);

  const float qscl = 0.08838834764831845f * 1.4426950408889634f;  // scale * log2(e)
  k_rope<2><<<2048, 256, 0, stream>>>(Ktmp, Kr, tab, 1.0f);  // K: 4 kv heads

  // attention: RoPE-Q fused into Q-load; AO written in place over Qtmp
  k_attn<<<dim3(8, 64), 256, 0, stream>>>(Qtmp, Kr, Vr, Qtmp, tab, qscl);

  // output projection: [8192 x 2048] @ [2048 x 2048]^T -> fp32, 256 blocks = 1.0 rounds
  k_gemm256<<<dim3(8, 32), 512, 0, stream>>>(Qtmp, woT, d_out ? (float*)d_out : nullptr, 2048);
}

// Round 14
// 329.477 us; speedup vs baseline: 1.1845x; 1.0058x over previous
//
#include <hip/hip_runtime.h>

typedef __bf16 bf16;
typedef float  f32x4  __attribute__((ext_vector_type(4)));
typedef float  f32x2  __attribute__((ext_vector_type(2)));
typedef float  f32x16 __attribute__((ext_vector_type(16)));
typedef __bf16 bf16x8 __attribute__((ext_vector_type(8)));
typedef __bf16 bf16x4 __attribute__((ext_vector_type(4)));
typedef unsigned short ushort4_ __attribute__((ext_vector_type(4)));
typedef unsigned int   uint2_   __attribute__((ext_vector_type(2)));

typedef unsigned int __attribute__((address_space(1))) uint_g;
typedef unsigned int __attribute__((address_space(3))) uint_l;

#define DEV __device__ __forceinline__

DEV void gload16(const void* g, void* l) {
  // async global->LDS, 16B per lane; LDS dst is wave-uniform base + lane*16
  __builtin_amdgcn_global_load_lds((uint_g*)g, (uint_l*)l, 16, 0, 0);
}

#define SBAR     asm volatile("s_barrier" ::: "memory")
#define VMCNT(n) asm volatile("s_waitcnt vmcnt(" #n ")" ::: "memory")
#define PHASE_SYNC do { \
  asm volatile("s_barrier" ::: "memory"); \
  asm volatile("s_waitcnt lgkmcnt(0)" ::: "memory"); \
  __builtin_amdgcn_sched_barrier(0); } while (0)

// ---------------- fp32 -> bf16 convert (vectorized) ----------------
__global__ void k_cvt(const float* __restrict__ in, bf16* __restrict__ out) {
  int i = blockIdx.x * 256 + threadIdx.x;          // one float4 per thread
  f32x4 v = *((const f32x4*)in + i);
  bf16x4 o;
  o[0] = (bf16)v[0]; o[1] = (bf16)v[1]; o[2] = (bf16)v[2]; o[3] = (bf16)v[3];
  *((bf16x4*)out + i) = o;
}

// ---------------- [K][N] fp32 -> [N][K] bf16 transpose ----------------
__global__ void k_transpose_cvt(const float* __restrict__ in, bf16* __restrict__ out,
                                int K, int N) {
  __shared__ bf16 tile[64][65];
  int n0 = blockIdx.x * 64, k0 = blockIdx.y * 64;
  int tx = threadIdx.x & 63, ty = threadIdx.x >> 6;
#pragma unroll
  for (int r = 0; r < 64; r += 4)
    tile[r + ty][tx] = (bf16)in[(size_t)(k0 + r + ty) * N + n0 + tx];
  __syncthreads();
#pragma unroll
  for (int r = 0; r < 64; r += 4)
    out[(size_t)(n0 + r + ty) * K + k0 + tx] = tile[tx][r + ty];
}

// ---------------- RoPE cos/sin table: [T][64] of (cos,sin) ----------------
__global__ void k_rope_tab(f32x2* __restrict__ tab) {
  int idx = blockIdx.x * 256 + threadIdx.x;   // T*64
  int t = idx >> 6, i = idx & 63;
  float inv = powf(10000.f, -(float)i * (1.f / 64.f));
  float ang = (float)t * inv;
  f32x2 cs; cs[0] = cosf(ang); cs[1] = sinf(ang);
  tab[idx] = cs;
}

// ---------------- 256x256 GEMM (out-proj): R8 phases + barrier-neutral counted vmcnt ----
// Stage order A0,A2 -> B0..B3 -> A1,A3 so the tile-end drain is vmcnt(2) (A1,A3 of t+1
// stay in flight; not read until P2 of t+1, gated there by vmcnt(8)).  Barrier count
// unchanged vs R8 (5/tile).  Last tile falls back to vmcnt(0) (pre==false).
__global__ __launch_bounds__(512, 1) void k_gemm256(const bf16* __restrict__ A,
                                                    const bf16* __restrict__ Bt,
                                                    float* __restrict__ C,
                                                    int K) {
  __shared__ bf16 Asm[2][256 * 64];
  __shared__ bf16 Bsm[2][256 * 64];
  const int tid = threadIdx.x;
  const int w = tid >> 6, l = tid & 63, lr = l & 15, lg = l >> 4;
  const int wr = w >> 2, wc = w & 3;
  const int bn = blockIdx.x, bm = blockIdx.y;

  const int srow = tid >> 3;                                    // 0..63
  const int scb = ((tid & 7) << 4) ^ ((srow & 7) << 4);         // pre-swizzled col byte
  const bf16* Ag = A  + ((size_t)(bm * 256) + srow) * K;
  const bf16* Bg = Bt + ((size_t)(bn * 256) + srow) * K;
  const int ldsbase = w << 10;                                  // per-wave 1KB slice

  auto stA = [&](int buf, int s, int k0) {
    gload16((const char*)Ag + ((size_t)(s * 64) * K + k0) * 2 + scb,
            (char*)&Asm[buf][0] + s * 8192 + ldsbase);
  };
  auto stB = [&](int buf, int s, int k0) {
    gload16((const char*)Bg + ((size_t)(s * 64) * K + k0) * 2 + scb,
            (char*)&Bsm[buf][0] + s * 8192 + ldsbase);
  };
  auto ldA = [&](int buf, int mf, int kk) -> bf16x8 {
    int row = wr * 128 + mf * 16 + lr;
    return *(const bf16x8*)((const char*)&Asm[buf][0] + row * 128 +
                            ((kk * 64 + lg * 16) ^ ((lr & 7) << 4)));
  };
  auto ldB = [&](int buf, int nf, int kk) -> bf16x8 {
    int row = wc * 64 + nf * 16 + lr;
    return *(const bf16x8*)((const char*)&Bsm[buf][0] + row * 128 +
                            ((kk * 64 + lg * 16) ^ ((lr & 7) << 4)));
  };

  f32x4 acc[8][4] = {};
  const int nt = K >> 6;

#pragma unroll
  for (int s = 0; s < 4; s++) { stA(0, s, 0); stB(0, s, 0); }
  VMCNT(0);
  __syncthreads();

#pragma unroll 1
  for (int t = 0; t < nt; t++) {
    const int cur = t & 1, nxt = cur ^ 1;
    const int kn = (t + 1) << 6;
    const bool pre = (t + 1 < nt);
    bf16x8 a0[4][2], a1[4][2], b0[2][2], b1[2][2];

    // ---- phase 0: read A m0-3, B n0-1; stage A0,A2(t+1) ----
#pragma unroll
    for (int mf = 0; mf < 4; mf++) { a0[mf][0] = ldA(cur, mf, 0); a0[mf][1] = ldA(cur, mf, 1); }
#pragma unroll
    for (int nf = 0; nf < 2; nf++) { b0[nf][0] = ldB(cur, nf, 0); b0[nf][1] = ldB(cur, nf, 1); }
    if (pre) { stA(nxt, 0, kn); stA(nxt, 2, kn); }
    PHASE_SYNC;
    __builtin_amdgcn_s_setprio(1);
#pragma unroll
    for (int mf = 0; mf < 4; mf++)
#pragma unroll
      for (int nf = 0; nf < 2; nf++)
#pragma unroll
        for (int kk = 0; kk < 2; kk++)
          acc[mf][nf] = __builtin_amdgcn_mfma_f32_16x16x32_bf16(a0[mf][kk], b0[nf][kk], acc[mf][nf], 0, 0, 0);
    __builtin_amdgcn_s_setprio(0);

    // ---- phase 1: read B n2-3; stage B0..B3(t+1) ----
#pragma unroll
    for (int nf = 0; nf < 2; nf++) { b1[nf][0] = ldB(cur, nf + 2, 0); b1[nf][1] = ldB(cur, nf + 2, 1); }
    if (pre) { stB(nxt, 0, kn); stB(nxt, 1, kn); stB(nxt, 2, kn); stB(nxt, 3, kn); }
    PHASE_SYNC;
    __builtin_amdgcn_s_setprio(1);
#pragma unroll
    for (int mf = 0; mf < 4; mf++)
#pragma unroll
      for (int nf = 0; nf < 2; nf++)
#pragma unroll
        for (int kk = 0; kk < 2; kk++)
          acc[mf][nf + 2] = __builtin_amdgcn_mfma_f32_16x16x32_bf16(a0[mf][kk], b1[nf][kk], acc[mf][nf + 2], 0, 0, 0);
    __builtin_amdgcn_s_setprio(0);

    // ---- phase 2: stage A1,A3(t+1); counted gate on A1,A3(t); read a1 AFTER barrier ----
    if (pre) { stA(nxt, 1, kn); stA(nxt, 3, kn); VMCNT(8); }
    else     { VMCNT(0); }
    SBAR;
    __builtin_amdgcn_sched_barrier(0);
#pragma unroll
    for (int mf = 0; mf < 4; mf++) { a1[mf][0] = ldA(cur, mf + 4, 0); a1[mf][1] = ldA(cur, mf + 4, 1); }
    __builtin_amdgcn_s_setprio(1);
#pragma unroll
    for (int mf = 0; mf < 4; mf++)
#pragma unroll
      for (int nf = 0; nf < 2; nf++)
#pragma unroll
        for (int kk = 0; kk < 2; kk++)
          acc[mf + 4][nf] = __builtin_amdgcn_mfma_f32_16x16x32_bf16(a1[mf][kk], b0[nf][kk], acc[mf + 4][nf], 0, 0, 0);
    __builtin_amdgcn_s_setprio(0);

    // ---- phase 3: MFMA then counted drain (A1,A3(t+1) keep flying) ----
    __builtin_amdgcn_s_setprio(1);
#pragma unroll
    for (int mf = 0; mf < 4; mf++)
#pragma unroll
      for (int nf = 0; nf < 2; nf++)
#pragma unroll
        for (int kk = 0; kk < 2; kk++)
          acc[mf + 4][nf + 2] = __builtin_amdgcn_mfma_f32_16x16x32_bf16(a1[mf][kk], b1[nf][kk], acc[mf + 4][nf + 2], 0, 0, 0);
    __builtin_amdgcn_s_setprio(0);
    if (pre) { VMCNT(2); } else { VMCNT(0); }
    SBAR;
  }

#pragma unroll
  for (int mf = 0; mf < 8; mf++) {
    const int rowb = bm * 256 + wr * 128 + mf * 16 + lg * 4;
#pragma unroll
    for (int nf = 0; nf < 4; nf++) {
      const int col = bn * 256 + wc * 64 + nf * 16 + lr;
#pragma unroll
      for (int j = 0; j < 4; j++)
        C[(size_t)(rowb + j) * 2048 + col] = acc[mf][nf][j];
    }
  }
}

// ---------------- 256x192 QKV GEMM: tail-exact grid + barrier-neutral counted vmcnt ----
// Stage order A0,A2 -> B0,B1,B2 -> A1,A3; tile-end vmcnt(2); P2 gate vmcnt(7).
__global__ __launch_bounds__(512, 1) void k_gemmQKV(const bf16* __restrict__ A,
                                                    const bf16* __restrict__ Bt,
                                                    bf16* __restrict__ Cq,
                                                    bf16* __restrict__ Ck,
                                                    bf16* __restrict__ Cv,
                                                    int K) {
  __shared__ bf16 Asm[2][256 * 64];
  __shared__ bf16 Bsm[2][192 * 64];
  const int tid = threadIdx.x;
  const int w = tid >> 6, l = tid & 63, lr = l & 15, lg = l >> 4;
  const int wr = w >> 2, wc = w & 3;
  const int bn = blockIdx.x, bm = blockIdx.y;

  const int srow = tid >> 3;                                    // 0..63
  const int scb = ((tid & 7) << 4) ^ ((srow & 7) << 4);         // pre-swizzled col byte
  const bf16* Ag = A  + ((size_t)(bm * 256) + srow) * K;
  const bf16* Bg = Bt + ((size_t)(bn * 192) + srow) * K;
  const int ldsbase = w << 10;                                  // per-wave 1KB slice

  auto stA = [&](int buf, int s, int k0) {
    gload16((const char*)Ag + ((size_t)(s * 64) * K + k0) * 2 + scb,
            (char*)&Asm[buf][0] + s * 8192 + ldsbase);
  };
  auto stB = [&](int buf, int s, int k0) {
    gload16((const char*)Bg + ((size_t)(s * 64) * K + k0) * 2 + scb,
            (char*)&Bsm[buf][0] + s * 8192 + ldsbase);
  };
  auto ldA = [&](int buf, int mf, int kk) -> bf16x8 {
    int row = wr * 128 + mf * 16 + lr;
    return *(const bf16x8*)((const char*)&Asm[buf][0] + row * 128 +
                            ((kk * 64 + lg * 16) ^ ((lr & 7) << 4)));
  };
  auto ldB = [&](int buf, int nf, int kk) -> bf16x8 {
    int row = wc * 48 + nf * 16 + lr;
    return *(const bf16x8*)((const char*)&Bsm[buf][0] + row * 128 +
                            ((kk * 64 + lg * 16) ^ ((lr & 7) << 4)));
  };

  f32x4 acc[8][3] = {};
  const int nt = K >> 6;

#pragma unroll
  for (int s = 0; s < 4; s++) stA(0, s, 0);
#pragma unroll
  for (int s = 0; s < 3; s++) stB(0, s, 0);
  VMCNT(0);
  __syncthreads();

#pragma unroll 1
  for (int t = 0; t < nt; t++) {
    const int cur = t & 1, nxt = cur ^ 1;
    const int kn = (t + 1) << 6;
    const bool pre = (t + 1 < nt);
    bf16x8 a0[4][2], a1[4][2], b01[2][2], b2[2];

    // ---- phase 0: read A m0-3, B n0-1; stage A0,A2(t+1); 16 MFMA ----
#pragma unroll
    for (int mf = 0; mf < 4; mf++) { a0[mf][0] = ldA(cur, mf, 0); a0[mf][1] = ldA(cur, mf, 1); }
#pragma unroll
    for (int nf = 0; nf < 2; nf++) { b01[nf][0] = ldB(cur, nf, 0); b01[nf][1] = ldB(cur, nf, 1); }
    if (pre) { stA(nxt, 0, kn); stA(nxt, 2, kn); }
    PHASE_SYNC;
    __builtin_amdgcn_s_setprio(1);
#pragma unroll
    for (int mf = 0; mf < 4; mf++)
#pragma unroll
      for (int nf = 0; nf < 2; nf++)
#pragma unroll
        for (int kk = 0; kk < 2; kk++)
          acc[mf][nf] = __builtin_amdgcn_mfma_f32_16x16x32_bf16(a0[mf][kk], b01[nf][kk], acc[mf][nf], 0, 0, 0);
    __builtin_amdgcn_s_setprio(0);

    // ---- phase 1: read B n2; stage B0,B1,B2(t+1); 8 MFMA ----
    b2[0] = ldB(cur, 2, 0); b2[1] = ldB(cur, 2, 1);
    if (pre) { stB(nxt, 0, kn); stB(nxt, 1, kn); stB(nxt, 2, kn); }
    PHASE_SYNC;
    __builtin_amdgcn_s_setprio(1);
#pragma unroll
    for (int mf = 0; mf < 4; mf++)
#pragma unroll
      for (int kk = 0; kk < 2; kk++)
        acc[mf][2] = __builtin_amdgcn_mfma_f32_16x16x32_bf16(a0[mf][kk], b2[kk], acc[mf][2], 0, 0, 0);
    __builtin_amdgcn_s_setprio(0);

    // ---- phase 2: stage A1,A3(t+1); counted gate on A1,A3(t); read a1 AFTER barrier ----
    if (pre) { stA(nxt, 1, kn); stA(nxt, 3, kn); VMCNT(7); }
    else     { VMCNT(0); }
    SBAR;
    __builtin_amdgcn_sched_barrier(0);
#pragma unroll
    for (int mf = 0; mf < 4; mf++) { a1[mf][0] = ldA(cur, mf + 4, 0); a1[mf][1] = ldA(cur, mf + 4, 1); }
    __builtin_amdgcn_s_setprio(1);
#pragma unroll
    for (int mf = 0; mf < 4; mf++)
#pragma unroll
      for (int nf = 0; nf < 2; nf++)
#pragma unroll
        for (int kk = 0; kk < 2; kk++)
          acc[mf + 4][nf] = __builtin_amdgcn_mfma_f32_16x16x32_bf16(a1[mf][kk], b01[nf][kk], acc[mf + 4][nf], 0, 0, 0);
    __builtin_amdgcn_s_setprio(0);

    // ---- phase 3: 8 MFMA; counted drain (A1,A3(t+1) keep flying) ----
    __builtin_amdgcn_s_setprio(1);
#pragma unroll
    for (int mf = 0; mf < 4; mf++)
#pragma unroll
      for (int kk = 0; kk < 2; kk++)
        acc[mf + 4][2] = __builtin_amdgcn_mfma_f32_16x16x32_bf16(a1[mf][kk], b2[kk], acc[mf + 4][2], 0, 0, 0);
    __builtin_amdgcn_s_setprio(0);
    if (pre) { VMCNT(2); } else { VMCNT(0); }
    SBAR;
  }

  // ---- epilogue: per-16-col-tile region split (boundaries 2048/2560 are x16) ----
#pragma unroll
  for (int mf = 0; mf < 8; mf++) {
    const int rowb = bm * 256 + wr * 128 + mf * 16 + lg * 4;
#pragma unroll
    for (int nf = 0; nf < 3; nf++) {
      const int c0 = bn * 192 + wc * 48 + nf * 16;   // lane-invariant tile base
      const int col = c0 + lr;
      if (c0 < 2048) {
#pragma unroll
        for (int j = 0; j < 4; j++)
          Cq[(size_t)(rowb + j) * 2048 + col] = (bf16)acc[mf][nf][j];
      } else if (c0 < 2560) {
        const int kcol = col - 2048;
#pragma unroll
        for (int j = 0; j < 4; j++)
          Ck[(size_t)(rowb + j) * 512 + kcol] = (bf16)acc[mf][nf][j];
      } else {
        const int vcol = col - 2560;                 // 0..511
        const int kv = vcol >> 7, d = vcol & 127;
        const int bb = rowb >> 11, t0 = rowb & 2047;
        const size_t off = ((size_t)((bb * 4 + kv) * 128 + d)) * 2048 + t0;
        ushort4_ pk;
#pragma unroll
        for (int j = 0; j < 4; j++)
          pk[j] = __builtin_bit_cast(unsigned short, (bf16)acc[mf][nf][j]);
        *(ushort4_*)(Cv + off) = pk;
      }
    }
  }
}

// ---------------- RoPE + rearrange: [B*T][NH*128] -> [B][NH][T][128] ----------------
template <int LOGNH>
__global__ void k_rope(const bf16* __restrict__ in, bf16* __restrict__ out,
                       const f32x2* __restrict__ tab, float scl) {
  const int NH = 1 << LOGNH;
  int idx = blockIdx.x * 256 + threadIdx.x;
  int dq = idx & 15;                        // d0 = dq*4
  int h = (idx >> 4) & (NH - 1);
  int bt = idx >> (4 + LOGNH);
  int t = bt & 2047;
  int d0 = dq * 4;
  const bf16* pin = in + (size_t)bt * (NH * 128) + h * 128;
  bf16x4 x1 = *(const bf16x4*)(pin + d0);
  bf16x4 x2 = *(const bf16x4*)(pin + 64 + d0);
  bf16x4 o1, o2;
#pragma unroll
  for (int j = 0; j < 4; j++) {
    f32x2 cs = tab[t * 64 + d0 + j];
    float c1 = cs[0] * scl, s1 = cs[1] * scl;
    float a = (float)x1[j], c2 = (float)x2[j];
    o1[j] = (bf16)(a * c1 - c2 * s1);
    o2[j] = (bf16)(c2 * c1 + a * s1);
  }
  int b = bt >> 11;
  bf16* pout = out + (((size_t)(b << LOGNH) + h) * 2048 + t) * 128;
  *(bf16x4*)(pout + d0) = o1;
  *(bf16x4*)(pout + 64 + d0) = o2;
}

// ---------------- flash attention (causal, GQA), 32x32 MFMA, pipelined dbuf ----------------
// R11 version (proven 128.4 us): 4 waves x 32 q-rows, paired blocks, K/V dbuf, one
// barrier/tile, RoPE-Q fused into Q-load, P via per-wave LDS roundtrip, AO in place.
__global__ __launch_bounds__(256, 2) void k_attn(const bf16* __restrict__ Qraw,
                                                 const bf16* __restrict__ Kb,
                                                 const bf16* __restrict__ Vt,
                                                 bf16* __restrict__ AO,
                                                 const f32x2* __restrict__ tab,
                                                 float qscl) {
  __shared__ bf16 Ks[2][64 * 128];  // 32KB, [kv 64][d 128] XOR-swizzled rows
  __shared__ bf16 Vs[2][128 * 64];  // 32KB, [d 128][kv 64] XOR-swizzled rows
  __shared__ bf16 Ps[4][32 * 64];   // 16KB, per-wave P[q 32][kv 64], swizzled
  const int tid = threadIdx.x, w = tid >> 6, l = tid & 63;
  const int bh = blockIdx.y, b = bh >> 4, h = bh & 15, kvh = h >> 2;
  const int pi = blockIdx.x;
  const int l31 = l & 31, hi = l >> 5;

  const bf16* Kh = Kb + (size_t)(b * 4 + kvh) * (2048 * 128);
  const bf16* Vh = Vt + (size_t)(b * 4 + kvh) * (128 * 2048);
  char* Pw = (char*)&Ps[w][0] + l31 * 128;   // this lane's q-row in the per-wave P tile
  const int qsw = (l & 7) << 4;              // row swizzle (q & 7) << 4

  auto stage = [&](int kv0, int buf) {
#pragma unroll
    for (int i = 0; i < 4; i++) {
      int krow = w * 16 + i * 4 + (l >> 4);
      int kcb = ((l & 15) * 16) ^ ((krow & 7) << 4);
      gload16(Kh + (size_t)(kv0 + krow) * 128 + (kcb >> 1), (bf16*)&Ks[buf][0] + w * 2048 + i * 512);
      int vrow = w * 32 + i * 8 + (l >> 3);
      int vcb = ((l & 7) * 16) ^ ((vrow & 7) << 4);
      gload16(Vh + (size_t)vrow * 2048 + kv0 + (vcb >> 1), (bf16*)&Vs[buf][0] + w * 2048 + i * 512);
    }
  };

#pragma unroll 1
  for (int ph = 0; ph < 2; ph++) {
    const int q0 = (ph ? (15 - pi) : pi) * 128;
    const int nt = q0 / 64 + 2;
    const int qw0 = q0 + w * 32;
    const int qg = qw0 + l31;

    // Q load (raw) + in-register RoPE + qscl fold:
    // qf[kk] covers d = kk*16 + hi*8 + j; pair (kk, kk+4) = (d, d+64), lane-local.
    bf16x8 qf[8];
    {
      const bf16* qp = Qraw + ((size_t)(b * 2048 + qg)) * 2048 + h * 128 + hi * 8;
      const f32x2* tb = tab + qg * 64 + hi * 8;
      bf16x8 xr[8];
#pragma unroll
      for (int kk = 0; kk < 8; kk++) xr[kk] = *(const bf16x8*)(qp + kk * 16);
#pragma unroll
      for (int kk = 0; kk < 4; kk++) {
#pragma unroll
        for (int j = 0; j < 8; j++) {
          f32x2 cs = tb[kk * 16 + j];
          float a = (float)xr[kk][j], c2 = (float)xr[kk + 4][j];
          qf[kk][j]     = (bf16)((a * cs[0] - c2 * cs[1]) * qscl);
          qf[kk + 4][j] = (bf16)((c2 * cs[0] + a * cs[1]) * qscl);
        }
      }
    }

    f32x16 ot[4] = {};               // O^T rows d = dt*32 + (r&3)+8*(r>>2)+4*hi, col q = l&31
    float m_ = -3e38f, l_ = 0.f;

    int cur = 0;
    stage(0, 0);
    __syncthreads();

#pragma unroll 1
    for (int t = 0; t < nt; t++) {
      const int kv0 = t * 64;
      if (t + 1 < nt) stage(kv0 + 64, cur ^ 1);

      if (kv0 <= qw0 + 31) {
        // S^T = K @ Q^T: st[nb], rows kv = kv0 + nb*32 + (r&3)+8*(r>>2)+4*hi, col q = l&31
        f32x16 st[2] = {};
        __builtin_amdgcn_s_setprio(1);
#pragma unroll
        for (int nb = 0; nb < 2; nb++) {
          const int row = nb * 32 + l31;
          const char* kbase = (const char*)&Ks[cur][0] + row * 256;
#pragma unroll
          for (int kk = 0; kk < 8; kk++) {
            bf16x8 kf = *(const bf16x8*)(kbase + ((kk * 32 + hi * 16) ^ qsw));
            st[nb] = __builtin_amdgcn_mfma_f32_32x32x16_bf16(kf, qf[kk], st[nb], 0, 0, 0);
          }
        }
        __builtin_amdgcn_s_setprio(0);

        // causal mask (diag tiles only); values already in log2 domain
        if (kv0 + 63 > qw0) {
#pragma unroll
          for (int nb = 0; nb < 2; nb++) {
            const int kvb = kv0 + nb * 32 + 4 * hi;
#pragma unroll
            for (int r = 0; r < 16; r++) {
              int kg = kvb + (r & 3) + 8 * (r >> 2);
              if (kg > qg) st[nb][r] = -3e38f;
            }
          }
        }
        // row max: in-lane tree + one cross-half shfl
        float mx = -3e38f;
#pragma unroll
        for (int nb = 0; nb < 2; nb++)
#pragma unroll
          for (int r = 0; r < 16; r++) mx = fmaxf(mx, st[nb][r]);
        mx = fmaxf(mx, __shfl_xor(mx, 32));
        // defer-max (THR = 8 in log2 domain)
        if (!__all(mx - m_ <= 8.f)) {
          float mnew = fmaxf(m_, mx);
          float corr = exp2f(m_ - mnew);
          m_ = mnew; l_ *= corr;
#pragma unroll
          for (int dt = 0; dt < 4; dt++)
#pragma unroll
            for (int r = 0; r < 16; r++) ot[dt][r] *= corr;
        }
        // P = exp2(s - m), row-sum; write P[q][kv] pairs to per-wave LDS (8B swizzled stores)
        float ls = 0.f;
#pragma unroll
        for (int nb = 0; nb < 2; nb++)
#pragma unroll
          for (int a = 0; a < 4; a++) {
            uint2_ pr;
#pragma unroll
            for (int half = 0; half < 2; half++) {
              float p0 = exp2f(st[nb][4 * a + 2 * half] - m_);
              float p1 = exp2f(st[nb][4 * a + 2 * half + 1] - m_);
              ls += p0 + p1;
              unsigned short b0 = __builtin_bit_cast(unsigned short, (bf16)p0);
              unsigned short b1 = __builtin_bit_cast(unsigned short, (bf16)p1);
              pr[half] = (unsigned int)b0 | ((unsigned int)b1 << 16);
            }
            *(uint2_*)(Pw + ((nb * 64 + a * 16 + hi * 8) ^ qsw)) = pr;
          }
        ls += __shfl_xor(ls, 32);
        l_ += ls;

        // O^T += V^T @ P^T  (B-frag read back: elem j = P[q][kb*16 + 8*hi + j])
        __builtin_amdgcn_s_setprio(1);
#pragma unroll
        for (int kb = 0; kb < 4; kb++) {
          bf16x8 pb = *(const bf16x8*)(Pw + ((kb * 32 + hi * 16) ^ qsw));
#pragma unroll
          for (int dt = 0; dt < 4; dt++) {
            const int vrow = dt * 32 + l31;
            const char* vp = (const char*)&Vs[cur][0] + vrow * 128 + ((kb * 32 + hi * 16) ^ qsw);
            bf16x8 vf = *(const bf16x8*)vp;
            ot[dt] = __builtin_amdgcn_mfma_f32_32x32x16_bf16(vf, pb, ot[dt], 0, 0, 0);
          }
        }
        __builtin_amdgcn_s_setprio(0);
      }

      __syncthreads();   // one barrier/tile: drains this wave's stage(t+1) (flew under
                         // compute) and aligns all waves before cur-buffer overwrite
      cur ^= 1;
    }

    // epilogue: O^T / l -> AO[b*T + q][h*128 + d]
    const float inv = 1.f / l_;
    bf16* op = AO + ((size_t)b * 2048 + qg) * 2048 + h * 128;
#pragma unroll
    for (int dt = 0; dt < 4; dt++)
#pragma unroll
      for (int rq = 0; rq < 4; rq++) {
        ushort4_ pk;
#pragma unroll
        for (int j = 0; j < 4; j++)
          pk[j] = __builtin_bit_cast(unsigned short, (bf16)(ot[dt][rq * 4 + j] * inv));
        *(ushort4_*)(op + dt * 32 + rq * 8 + hi * 4) = pk;
      }
  }
}

// ---------------- launch ----------------
extern "C" void kernel_launch(void* const* d_in, const int* in_sizes, int n_in,
                              void* d_out, int out_size, void* d_ws, size_t ws_size,
                              hipStream_t stream) {
  const float* x  = (const float*)d_in[0];
  // d_in[1] = additive causal mask: implemented analytically, not read
  const float* wq = (const float*)d_in[2];
  const float* wk = (const float*)d_in[3];
  const float* wv = (const float*)d_in[4];
  const float* wo = (const float*)d_in[5];

  char* p = (char*)d_ws;
  auto alloc = [&](size_t bytes) { char* r = p; p += (bytes + 255) & ~(size_t)255; return r; };
  bf16*  xb     = (bf16*)alloc(8192ull * 2048 * 2);
  bf16*  wqkvT  = (bf16*)alloc(3072ull * 2048 * 2);   // rows: 0-2047 wq^T, 2048-2559 wk^T, 2560-3071 wv^T
  bf16*  woT    = (bf16*)alloc(2048ull * 2048 * 2);
  f32x2* tab    = (f32x2*)alloc(2048ull * 64 * 8);
  bf16*  Qtmp   = (bf16*)alloc(8192ull * 2048 * 2);   // raw Q; attention writes AO in place
  bf16*  Ktmp   = (bf16*)alloc(8192ull * 512 * 2);
  bf16*  Kr     = (bf16*)alloc(8192ull * 512 * 2);
  bf16*  Vr     = (bf16*)alloc(8192ull * 512 * 2);

  k_cvt<<<16384, 256, 0, stream>>>(x, xb);
  k_transpose_cvt<<<dim3(32, 32), 256, 0, stream>>>(wq, wqkvT, 2048, 2048);
  k_transpose_cvt<<<dim3(8, 32),  256, 0, stream>>>(wk, wqkvT + 2048ull * 2048, 2048, 512);
  k_transpose_cvt<<<dim3(8, 32),  256, 0, stream>>>(wv, wqkvT + 2560ull * 2048, 2048, 512);
  k_transpose_cvt<<<dim3(32, 32), 256, 0, stream>>>(wo, woT, 2048, 2048);
  k_rope_tab<<<512, 256, 0, stream>>>(tab);

  // fused QKV projection: [8192 x 2048] @ [3072 x 2048]^T, 256x192 tiles, 512 blocks = 2.0 rounds
  k_gemmQKV<<<dim3(16, 32), 512, 0, stream>>>(xb, wqkvT, Qtmp, Ktmp, Vr, 2048);

  const float qscl = 0.08838834764831845f * 1.4426950408889634f;  // scale * log2(e)
  k_rope<2><<<2048, 256, 0, stream>>>(Ktmp, Kr, tab, 1.0f);  // K: 4 kv heads

  // attention: RoPE-Q fused into Q-load; AO written in place over Qtmp
  k_attn<<<dim3(8, 64), 256, 0, stream>>>(Qtmp, Kr, Vr, Qtmp, tab, qscl);

  // output projection: [8192 x 2048] @ [2048 x 2048]^T -> fp32, 256 blocks = 1.0 rounds
  k_gemm256<<<dim3(8, 32), 512, 0, stream>>>(Qtmp, woT, (float*)d_out, 2048);
}